// Round 1
// baseline (1111.337 us; speedup 1.0000x reference)
//
#include <hip/hip_runtime.h>
#include <hip/hip_bf16.h>

// Problem constants
#define T_STEPS 256
#define B_SZ    4096
#define I_SZ    144
#define H_SZ    32
#define W_LD    176   // H + I

// photonic sigmoid constants
#define PS_A1   0.06f
#define PS_A2   1.005f
#define PS_X0   0.145f
#define PS_D    0.033f
#define PS_CUT  2.0f

// -----------------------------------------------------------------------------
// Kernel 1: U[row][j] = sum_i x[row][i] * Wx[j][i] + b[j]
// row = t_local*B + b  (within a T-chunk). One thread per row.
// x rows are 144 floats = 36 float4s. W loads are wave-uniform -> s_load.
// -----------------------------------------------------------------------------
__global__ __launch_bounds__(256) void gemm_u(
    const float* __restrict__ x,     // [nrows][144]
    const float* __restrict__ W,     // [32][176], Wx = cols 32..175
    const float* __restrict__ bias,  // [32]
    float* __restrict__ U,           // [nrows][32]
    int nrows)
{
    int row = blockIdx.x * blockDim.x + threadIdx.x;
    if (row >= nrows) return;
    const float* xr = x + (size_t)row * I_SZ;

    float acc[H_SZ];
#pragma unroll
    for (int j = 0; j < H_SZ; ++j) acc[j] = bias[j];

#pragma unroll 4
    for (int q = 0; q < I_SZ / 4; ++q) {
        float4 xv = *(const float4*)(xr + 4 * q);
#pragma unroll
        for (int j = 0; j < H_SZ; ++j) {
            // wave-uniform address -> scalar load
            float4 wv = *(const float4*)(W + j * W_LD + H_SZ + 4 * q);
            acc[j] = fmaf(xv.x, wv.x,
                     fmaf(xv.y, wv.y,
                     fmaf(xv.z, wv.z,
                     fmaf(xv.w, wv.w, acc[j]))));
        }
    }

    float* ur = U + (size_t)row * H_SZ;
#pragma unroll
    for (int j = 0; j < H_SZ; j += 4) {
        *(float4*)(ur + j) = make_float4(acc[j], acc[j+1], acc[j+2], acc[j+3]);
    }
}

// -----------------------------------------------------------------------------
// Kernel 2: recurrence  h = ps(h @ Wh.T + U[t])
// Block = 64 threads = 1 wave = 2 batch elements.
// lane = g*32 + j ; h_j kept in a register; Wh row j in 32 registers.
// Broadcast of the group's h vector via LDS (wave-internal, barrier elides).
// -----------------------------------------------------------------------------
__global__ __launch_bounds__(64) void recur(
    const float* __restrict__ U,     // [Tc][B][32]
    const float* __restrict__ W,     // [32][176], Wh = cols 0..31
    float* __restrict__ hout,        // [B][32] running h state / final output
    int Tc, int first)
{
    const int tid = threadIdx.x;
    const int j   = tid & 31;
    const int g   = tid >> 5;
    const int b   = blockIdx.x * 2 + g;

    // Wh row j -> registers
    float wh[H_SZ];
#pragma unroll
    for (int k = 0; k < H_SZ; k += 4) {
        float4 wv = *(const float4*)(W + j * W_LD + k);
        wh[k] = wv.x; wh[k+1] = wv.y; wh[k+2] = wv.z; wh[k+3] = wv.w;
    }

    __shared__ float hs[64];

    float h;
    if (first) h = 0.0f;
    else       h = hout[(size_t)b * H_SZ + j];

    const float*  Up     = U + (size_t)b * H_SZ + j;
    const size_t  stride = (size_t)B_SZ * H_SZ;

    // depth-2 prefetch pipeline for U
    float un0 = Up[0];
    float un1 = (Tc > 1) ? Up[stride] : 0.0f;

    const float expC = (float)(1.0 / (0.033 * 0.6931471805599453)); // 1/(D*ln2)

    for (int t = 0; t < Tc; ++t) {
        float u = un0;
        un0 = un1;
        int tn = (t + 2 < Tc) ? (t + 2) : (Tc - 1);
        un1 = Up[(size_t)tn * stride];

        // publish h for my group, then read the group's 32 h values
        hs[tid] = h;
        __syncthreads();   // single-wave workgroup: elided to waitcnt ordering

        float z = u;
#pragma unroll
        for (int k = 0; k < H_SZ; k += 4) {
            float4 hq = *(const float4*)&hs[g * 32 + k];  // broadcast read
            z = fmaf(wh[k],   hq.x,
                fmaf(wh[k+1], hq.y,
                fmaf(wh[k+2], hq.z,
                fmaf(wh[k+3], hq.w, z))));
        }
        __syncthreads();

        // photonic sigmoid: A2 + (A1-A2)/(1+exp(min(z-X0,CUT)/D))
        float zz = fminf(z - PS_X0, PS_CUT);
        float e  = exp2f(zz * expC);
        h = PS_A2 + (PS_A1 - PS_A2) / (1.0f + e);
    }

    hout[(size_t)b * H_SZ + j] = h;
}

// -----------------------------------------------------------------------------
extern "C" void kernel_launch(void* const* d_in, const int* in_sizes, int n_in,
                              void* d_out, int out_size, void* d_ws, size_t ws_size,
                              hipStream_t stream)
{
    const float* x    = (const float*)d_in[0];  // [256][4096][144]
    const float* W    = (const float*)d_in[1];  // [32][176]
    const float* bias = (const float*)d_in[2];  // [32]
    float* out = (float*)d_out;                 // [4096][32]
    float* U   = (float*)d_ws;

    // choose T-chunk that fits in workspace
    int Tc = T_STEPS;
    while ((size_t)Tc * B_SZ * H_SZ * sizeof(float) > ws_size && Tc > 1) Tc >>= 1;

    for (int t0 = 0; t0 < T_STEPS; t0 += Tc) {
        int tc = (t0 + Tc <= T_STEPS) ? Tc : (T_STEPS - t0);
        int nrows = tc * B_SZ;
        gemm_u<<<(nrows + 255) / 256, 256, 0, stream>>>(
            x + (size_t)t0 * B_SZ * I_SZ, W, bias, U, nrows);
        recur<<<B_SZ / 2, 64, 0, stream>>>(U, W, out, tc, t0 == 0 ? 1 : 0);
    }
}